// Round 15
// baseline (91.076 us; speedup 1.0000x reference)
//
#include <hip/hip_runtime.h>

// Bahdanau attention. query [8][400][256], y [8][400][256], Wq_w [128][256],
// Wq_b [128], Wy_w [128][256], Wy_b [128], v_w [1][128], v_b (dropped:
// softmax shift-invariant), n_wins_y [8] i32. out [8][400][256] f32.
//
// score = sum_a v_a*tanh(qp+yp) ~ const + sum_a (-2 v_a)/(Eq_a*Ey_a + 1),
// Eq = e^{2 qp}, Ey = e^{2 yp} precomputed (1 fma/elem + 1 rcp/4).
//
// Lesson stack:
//  R4:  no runtime-indexed register arrays (scratch spill).
//  R7:  no lane-scattered global reads (W transposed in K0).
//  R10: broadcast loads scalarize ONLY if workgroup-uniform.
//  R11/R12: register-lean inner loops starve VGPRs & serialize latency.
//  R15: apply was LDS-pipe-bound (stage 1KB/row + reread 16B/lane/t). y rows
//       are read ONCE per block -> no reuse -> drop LDS staging, read y direct
//       from global (L2/L3-resident, 128B coalesced 8-way bcast) with depth-2
//       named-register pipeline; p stays in conflict-free LDS (PROW=404:
//       q*404 mod 32 = {0,20,8,28,16,4,24,12} -> 8 disjoint bank-quads).

#define LOG2E 1.4426950408889634f
#define TANH_SCALE 2.8853900817779268f  // 2*log2(e)

constexpr int TQn = 400, TYn = 400, AD = 128, DD = 256;
constexpr int PROW = 404;  // s_p row stride (floats), 16B-aligned rows

// ---------------- K0: WT4[k4][a] = W[a][4k4..4k4+3]; vneg = -2v ------------
__global__ __launch_bounds__(128) void transpose_kernel(
    const float* __restrict__ Wq, const float* __restrict__ Wy,
    const float* __restrict__ vw,
    float4* __restrict__ WTq, float4* __restrict__ WTy,
    float* __restrict__ vneg)
{
    const int k4 = blockIdx.x & 63;
    const bool isq = blockIdx.x < 64;
    const float4* src = reinterpret_cast<const float4*>(isq ? Wq : Wy);
    float4* dst = isq ? WTq : WTy;
    const int a = threadIdx.x;                 // 0..127
    dst[k4 * 128 + a] = src[a * 64 + k4];
    if (blockIdx.x == 0) vneg[a] = -2.f * vw[a];
}

// ---------------- K1: proj -> EqS packed / EyT transposed (R14-proven) -----
// 4 rows/block, 1600 blocks x 256 thr (a = tid&127, k-half = tid>>7).
// EqS[qgrp 400][a4 32][q 8][4] ; EyT[a4 32][3200 rows][4]
__global__ __launch_bounds__(256, 4) void proj_kernel(
    const float* __restrict__ qin, const float* __restrict__ yin,
    const float4* __restrict__ WTq, const float* __restrict__ bq,
    const float4* __restrict__ WTy, const float* __restrict__ by,
    float* __restrict__ EqS, float* __restrict__ EyT)
{
    const int blk = blockIdx.x;               // [0,800) q, [800,1600) y
    const bool is_q = blk < 800;
    const int row0 = (is_q ? blk : blk - 800) * 4;   // global row (b folded)
    const float* in   = (is_q ? qin : yin) + (size_t)row0 * DD;
    const float4* wt  = is_q ? WTq : WTy;     // [64 k4][128 a]
    const float* bias = is_q ? bq : by;

    __shared__ float lin[4 * DD];             // 4 KB
    __shared__ float red[4][AD];              // 2 KB
    {
        const float4* in4 = reinterpret_cast<const float4*>(in);
        reinterpret_cast<float4*>(lin)[threadIdx.x] = in4[threadIdx.x];  // 1/thread
    }
    __syncthreads();

    const int a = threadIdx.x & 127;
    const int h = threadIdx.x >> 7;           // k-half
    float acc[4] = {0.f, 0.f, 0.f, 0.f};
    const float4* l4 = reinterpret_cast<const float4*>(lin);
    #pragma unroll 8
    for (int i = 0; i < 32; ++i) {
        const int k4 = h * 32 + i;
        float4 w4 = wt[k4 * 128 + a];         // coalesced 16B/lane
        #pragma unroll
        for (int r = 0; r < 4; ++r) {
            float4 v = l4[r * 64 + k4];       // LDS broadcast (wave-uniform)
            acc[r] = fmaf(w4.x, v.x, acc[r]);
            acc[r] = fmaf(w4.y, v.y, acc[r]);
            acc[r] = fmaf(w4.z, v.z, acc[r]);
            acc[r] = fmaf(w4.w, v.w, acc[r]);
        }
    }
    if (h) {
        #pragma unroll
        for (int r = 0; r < 4; ++r) red[r][a] = acc[r];
    }
    __syncthreads();
    if (!h) {
        const float bb = bias[a];
        const int a4 = a >> 2, ac = a & 3;
        const int qoff = (row0 & 7);          // 0 or 4 within the 8q group
        #pragma unroll
        for (int r = 0; r < 4; ++r) {
            const float e = __builtin_amdgcn_exp2f(
                (acc[r] + red[r][a] + bb) * TANH_SCALE);
            if (is_q)
                EqS[(size_t)(row0 >> 3) * 1024 + a4 * 32 + (qoff + r) * 4 + ac] = e;
            else
                EyT[(size_t)a4 * 12800 + (size_t)(row0 + r) * 4 + ac] = e;
        }
    }
}

// ---------------- K2: raw scores (R14-proven); zero LDS/barriers; 4q -------
__global__ __launch_bounds__(448, 2) void score_kernel(
    const float* __restrict__ EqS,   // [400 qgrp][32][8][4]
    const float4* __restrict__ EyT4, // [32][3200]
    const float* __restrict__ vneg,  // [128] = -2v
    const int*  __restrict__ nwins,  // [B]
    float* __restrict__ s)           // [B][TQ][TY]
{
    const int grp = blockIdx.x;               // b*100 + qg
    const int b   = grp / 100;
    const int qg  = grp % 100;
    const int q0  = qg * 4;
    const int n   = nwins[b];
    const int t   = threadIdx.x;              // 0..447
    if ((t & ~63) >= n) return;               // wave-uniform early exit

    const int ycol = b * TYn + min(t, TYn - 1);
    const float4* eqg = reinterpret_cast<const float4*>(EqS)
                      + (size_t)(b * 50 + (qg >> 1)) * 256 + 4 * (qg & 1);
    const float4* vn4 = reinterpret_cast<const float4*>(vneg);

    float ac0 = 0.f, ac1 = 0.f, ac2 = 0.f, ac3 = 0.f;
    for (int a4 = 0; a4 < 32; ++a4) {
        const float4 ey = EyT4[(size_t)a4 * 3200 + ycol];  // coalesced 1KB
        const float4* eqa = eqg + a4 * 8;                  // uniform -> s_load
        const float4 vv = vn4[a4];                         // uniform -> s_load
        const float4 e0 = eqa[0], e1 = eqa[1], e2 = eqa[2], e3 = eqa[3];
        #define SCORE_Q(ACC, EQ)                                            \
        {                                                                   \
            float a0 = fmaf(EQ.x, ey.x, 1.f);                               \
            float a1 = fmaf(EQ.y, ey.y, 1.f);                               \
            float a2 = fmaf(EQ.z, ey.z, 1.f);                               \
            float a3 = fmaf(EQ.w, ey.w, 1.f);                               \
            float p01 = a0 * a1, p23 = a2 * a3;                             \
            float R = __builtin_amdgcn_rcpf(p01 * p23);                     \
            float u = p23 * R, w = p01 * R;                                 \
            ACC = fmaf(vv.x, a1 * u, ACC);                                  \
            ACC = fmaf(vv.y, a0 * u, ACC);                                  \
            ACC = fmaf(vv.z, a3 * w, ACC);                                  \
            ACC = fmaf(vv.w, a2 * w, ACC);                                  \
        }
        SCORE_Q(ac0, e0) SCORE_Q(ac1, e1) SCORE_Q(ac2, e2) SCORE_Q(ac3, e3)
        #undef SCORE_Q
    }
    if (t < n) {
        float* srow = s + (size_t)(b * TQn + q0) * TYn + t;
        srow[0 * TYn] = ac0; srow[1 * TYn] = ac1;
        srow[2 * TYn] = ac2; srow[3 * TYn] = ac3;
    }
}

// ---------------- K3: softmax + att@y; 8q/block, y direct from global ------
__global__ __launch_bounds__(512, 2) void apply_kernel(
    const float* __restrict__ y,    // [B][TY][DD]
    const float* __restrict__ s,    // [B][TQ][TY]
    const int*  __restrict__ nwins, // [B]
    float* __restrict__ out)        // [B][TQ][DD]
{
    const int bid = blockIdx.x;               // 8 * 50
    const int b   = bid / 50;
    const int q0  = (bid % 50) * 8;
    const int tid = threadIdx.x, wave = tid >> 6, lane = tid & 63;
    const int n = nwins[b];
    const float NEG_INF = -__builtin_inff();

    __shared__ __align__(16) float s_p[8][PROW];   // 12.9 KB

    // ---- softmax for q = q0 + wave (8 waves, proven form) ----
    const float* srow = s + (size_t)(b * TQn + q0 + wave) * TYn;
    float sc0, sc1, sc2, sc3, sc4, sc5, sc6;
    {
        int t;
        t = 0 * 64 + lane; sc0 = (t < n) ? srow[t] : NEG_INF;
        t = 1 * 64 + lane; sc1 = (t < n) ? srow[t] : NEG_INF;
        t = 2 * 64 + lane; sc2 = (t < n) ? srow[t] : NEG_INF;
        t = 3 * 64 + lane; sc3 = (t < n) ? srow[t] : NEG_INF;
        t = 4 * 64 + lane; sc4 = (t < n) ? srow[t] : NEG_INF;
        t = 5 * 64 + lane; sc5 = (t < n) ? srow[t] : NEG_INF;
        t = 6 * 64 + lane; sc6 = (t < n) ? srow[t] : NEG_INF;
    }
    float m = fmaxf(fmaxf(fmaxf(sc0, sc1), fmaxf(sc2, sc3)),
                    fmaxf(fmaxf(sc4, sc5), sc6));
    #pragma unroll
    for (int off = 32; off >= 1; off >>= 1) m = fmaxf(m, __shfl_xor(m, off, 64));
    sc0 = __builtin_amdgcn_exp2f((sc0 - m) * LOG2E);
    sc1 = __builtin_amdgcn_exp2f((sc1 - m) * LOG2E);
    sc2 = __builtin_amdgcn_exp2f((sc2 - m) * LOG2E);
    sc3 = __builtin_amdgcn_exp2f((sc3 - m) * LOG2E);
    sc4 = __builtin_amdgcn_exp2f((sc4 - m) * LOG2E);
    sc5 = __builtin_amdgcn_exp2f((sc5 - m) * LOG2E);
    sc6 = __builtin_amdgcn_exp2f((sc6 - m) * LOG2E);
    float l = ((sc0 + sc1) + (sc2 + sc3)) + ((sc4 + sc5) + sc6);
    #pragma unroll
    for (int off = 32; off >= 1; off >>= 1) l += __shfl_xor(l, off, 64);
    const float inv = 1.0f / l;
    s_p[wave][0 * 64 + lane] = sc0 * inv;     // zeros beyond n (exp2(-inf)=0)
    s_p[wave][1 * 64 + lane] = sc1 * inv;
    s_p[wave][2 * 64 + lane] = sc2 * inv;
    s_p[wave][3 * 64 + lane] = sc3 * inv;
    s_p[wave][4 * 64 + lane] = sc4 * inv;
    s_p[wave][5 * 64 + lane] = sc5 * inv;
    {
        const int t = 6 * 64 + lane;          // 384..447: keep within [PROW)
        if (t < TYn) s_p[wave][t] = sc6 * inv;
    }
    __syncthreads();  // s_p visible; floats [400,404) never read (t4<100)

    // ---- apply: thread = (q = lane>>3, d4 = wave*8 + lane&7) ----
    // Unconditional 100 quads (p==0 beyond n). Depth-2 named A/B pipeline.
    const int q  = lane >> 3;                  // 0..7
    const int d4 = (wave << 3) | (lane & 7);   // 0..63
    const float4* prow4 = reinterpret_cast<const float4*>(&s_p[q][0]);
    const float4* yb4 = reinterpret_cast<const float4*>(y) + (size_t)(b * TYn) * 64;
    float4 acc = {0.f, 0.f, 0.f, 0.f};

    // preload quads 0 and 1 (rows 0..7; always valid)
    float4 a0 = yb4[      d4], a1 = yb4[ 64 + d4], a2 = yb4[128 + d4], a3 = yb4[192 + d4];
    float4 b0 = yb4[256 + d4], b1 = yb4[320 + d4], b2 = yb4[384 + d4], b3 = yb4[448 + d4];

    #pragma unroll 2
    for (int t4 = 0; t4 < 100; t4 += 2) {
        {   // quad t4 (A set)
            const float4 pv = prow4[t4];       // b128, 8 disjoint bank-quads
            acc.x = fmaf(pv.x, a0.x, acc.x); acc.y = fmaf(pv.x, a0.y, acc.y);
            acc.z = fmaf(pv.x, a0.z, acc.z); acc.w = fmaf(pv.x, a0.w, acc.w);
            acc.x = fmaf(pv.y, a1.x, acc.x); acc.y = fmaf(pv.y, a1.y, acc.y);
            acc.z = fmaf(pv.y, a1.z, acc.z); acc.w = fmaf(pv.y, a1.w, acc.w);
            acc.x = fmaf(pv.z, a2.x, acc.x); acc.y = fmaf(pv.z, a2.y, acc.y);
            acc.z = fmaf(pv.z, a2.z, acc.z); acc.w = fmaf(pv.z, a2.w, acc.w);
            acc.x = fmaf(pv.w, a3.x, acc.x); acc.y = fmaf(pv.w, a3.y, acc.y);
            acc.z = fmaf(pv.w, a3.z, acc.z); acc.w = fmaf(pv.w, a3.w, acc.w);
            if (t4 + 2 < 100) {                // reload A with quad t4+2
                const float4* yr = yb4 + (size_t)(t4 + 2) * 256;
                a0 = yr[d4]; a1 = yr[64 + d4]; a2 = yr[128 + d4]; a3 = yr[192 + d4];
            }
        }
        {   // quad t4+1 (B set)
            const float4 pv = prow4[t4 + 1];
            acc.x = fmaf(pv.x, b0.x, acc.x); acc.y = fmaf(pv.x, b0.y, acc.y);
            acc.z = fmaf(pv.x, b0.z, acc.z); acc.w = fmaf(pv.x, b0.w, acc.w);
            acc.x = fmaf(pv.y, b1.x, acc.x); acc.y = fmaf(pv.y, b1.y, acc.y);
            acc.z = fmaf(pv.y, b1.z, acc.z); acc.w = fmaf(pv.y, b1.w, acc.w);
            acc.x = fmaf(pv.z, b2.x, acc.x); acc.y = fmaf(pv.z, b2.y, acc.y);
            acc.z = fmaf(pv.z, b2.z, acc.z); acc.w = fmaf(pv.z, b2.w, acc.w);
            acc.x = fmaf(pv.w, b3.x, acc.x); acc.y = fmaf(pv.w, b3.y, acc.y);
            acc.z = fmaf(pv.w, b3.z, acc.z); acc.w = fmaf(pv.w, b3.w, acc.w);
            if (t4 + 3 < 100) {                // reload B with quad t4+3
                const float4* yr = yb4 + (size_t)(t4 + 3) * 256;
                b0 = yr[d4]; b1 = yr[64 + d4]; b2 = yr[128 + d4]; b3 = yr[192 + d4];
            }
        }
    }
    reinterpret_cast<float4*>(out)[(size_t)(b * TQn + q0 + q) * 64 + d4] = acc;
}

extern "C" void kernel_launch(void* const* d_in, const int* in_sizes, int n_in,
                              void* d_out, int out_size, void* d_ws, size_t ws_size,
                              hipStream_t stream) {
    const float* query = (const float*)d_in[0];
    const float* y     = (const float*)d_in[1];
    const float* Wq_w  = (const float*)d_in[2];
    const float* Wq_b  = (const float*)d_in[3];
    const float* Wy_w  = (const float*)d_in[4];
    const float* Wy_b  = (const float*)d_in[5];
    const float* v_w   = (const float*)d_in[6];
    // d_in[7] = v_b: softmax-invariant, dropped.
    const int* nw      = (const int*)d_in[8];
    float* out = (float*)d_out;

    float4* WTq  = (float4*)d_ws;                    // 131 KB
    float4* WTy  = WTq + 64 * 128;                   // 131 KB
    float*  vneg = (float*)(WTy + 64 * 128);         // 512 B (pad 1 KB)
    float*  EqS  = vneg + 256;                       // [400][32][8][4] = 1.64 MB
    float*  EyT  = EqS + (size_t)400 * 1024;         // [32][3200][4]  = 1.64 MB
    float*  s    = EyT + (size_t)32 * 3200 * 4;      // [8][400][400]  = 5.12 MB

    transpose_kernel<<<128, 128, 0, stream>>>(Wq_w, Wy_w, v_w, WTq, WTy, vneg);
    proj_kernel<<<1600, 256, 0, stream>>>(query, y, WTq, Wq_b, WTy, Wy_b, EqS, EyT);
    score_kernel<<<8 * 100, 448, 0, stream>>>(
        EqS, (const float4*)EyT, vneg, nw, s);
    apply_kernel<<<8 * 50, 512, 0, stream>>>(y, s, nw, out);
}

// Round 17
// 60.286 us; speedup vs baseline: 1.5107x; 1.5107x over previous
//
#include <hip/hip_runtime.h>

// Bahdanau attention. query [8][400][256], y [8][400][256], Wq_w [128][256],
// Wq_b [128], Wy_w [128][256], Wy_b [128], v_w [1][128], v_b (dropped:
// softmax shift-invariant), n_wins_y [8] i32. out [8][400][256] f32.
//
// score = sum_a v_a*tanh(qp+yp) ~ const + sum_a (-2 v_a)/(Eq_a*Ey_a + 1),
// Eq = e^{2 qp}, Ey = e^{2 yp} precomputed (1 fma/elem + 1 rcp/4).
//
// Lesson stack:
//  R4:  no runtime-indexed register arrays (scratch spill).
//  R7:  no lane-scattered global reads (W transposed in K0).
//  R10: broadcast loads scalarize ONLY if workgroup-uniform.
//  R11/R12: register-lean inner loops starve VGPRs & serialize latency.
//  R15: global loads must be LANE-UNIQUE: 8-way-duplicated 128B loads ->
//       8x VMEM instrs + exposed latency (51.9us apply, VALUBusy 17%).
//  R16: apply = wave-owns-row: lane=d4 (1KB unique coalesced global y, each
//       row read once per block), 8 named per-q f4 accumulators, p via 2
//       same-address b128 broadcasts from stride-12 pT, depth-2 pipeline,
//       4-phase LDS cross-wave reduce. (R16 fix: no #pragma inside macro —
//       reduce phases as a lambda.)

#define LOG2E 1.4426950408889634f
#define TANH_SCALE 2.8853900817779268f  // 2*log2(e)

constexpr int TQn = 400, TYn = 400, AD = 128, DD = 256;
constexpr int PTS = 12;  // pT row stride in floats (48B: 16B-aligned, b128-readable)

// ---------------- K0: WT4[k4][a] = W[a][4k4..4k4+3]; vneg = -2v ------------
__global__ __launch_bounds__(128) void transpose_kernel(
    const float* __restrict__ Wq, const float* __restrict__ Wy,
    const float* __restrict__ vw,
    float4* __restrict__ WTq, float4* __restrict__ WTy,
    float* __restrict__ vneg)
{
    const int k4 = blockIdx.x & 63;
    const bool isq = blockIdx.x < 64;
    const float4* src = reinterpret_cast<const float4*>(isq ? Wq : Wy);
    float4* dst = isq ? WTq : WTy;
    const int a = threadIdx.x;                 // 0..127
    dst[k4 * 128 + a] = src[a * 64 + k4];
    if (blockIdx.x == 0) vneg[a] = -2.f * vw[a];
}

// ---------------- K1: proj -> EqS packed / EyT transposed (R14-proven) -----
__global__ __launch_bounds__(256, 4) void proj_kernel(
    const float* __restrict__ qin, const float* __restrict__ yin,
    const float4* __restrict__ WTq, const float* __restrict__ bq,
    const float4* __restrict__ WTy, const float* __restrict__ by,
    float* __restrict__ EqS, float* __restrict__ EyT)
{
    const int blk = blockIdx.x;               // [0,800) q, [800,1600) y
    const bool is_q = blk < 800;
    const int row0 = (is_q ? blk : blk - 800) * 4;   // global row (b folded)
    const float* in   = (is_q ? qin : yin) + (size_t)row0 * DD;
    const float4* wt  = is_q ? WTq : WTy;     // [64 k4][128 a]
    const float* bias = is_q ? bq : by;

    __shared__ float lin[4 * DD];             // 4 KB
    __shared__ float red[4][AD];              // 2 KB
    {
        const float4* in4 = reinterpret_cast<const float4*>(in);
        reinterpret_cast<float4*>(lin)[threadIdx.x] = in4[threadIdx.x];  // 1/thread
    }
    __syncthreads();

    const int a = threadIdx.x & 127;
    const int h = threadIdx.x >> 7;           // k-half
    float acc[4] = {0.f, 0.f, 0.f, 0.f};
    const float4* l4 = reinterpret_cast<const float4*>(lin);
    #pragma unroll 8
    for (int i = 0; i < 32; ++i) {
        const int k4 = h * 32 + i;
        float4 w4 = wt[k4 * 128 + a];         // coalesced 16B/lane
        #pragma unroll
        for (int r = 0; r < 4; ++r) {
            float4 v = l4[r * 64 + k4];       // LDS broadcast (wave-uniform)
            acc[r] = fmaf(w4.x, v.x, acc[r]);
            acc[r] = fmaf(w4.y, v.y, acc[r]);
            acc[r] = fmaf(w4.z, v.z, acc[r]);
            acc[r] = fmaf(w4.w, v.w, acc[r]);
        }
    }
    if (h) {
        #pragma unroll
        for (int r = 0; r < 4; ++r) red[r][a] = acc[r];
    }
    __syncthreads();
    if (!h) {
        const float bb = bias[a];
        const int a4 = a >> 2, ac = a & 3;
        const int qoff = (row0 & 7);          // 0 or 4 within the 8q group
        #pragma unroll
        for (int r = 0; r < 4; ++r) {
            const float e = __builtin_amdgcn_exp2f(
                (acc[r] + red[r][a] + bb) * TANH_SCALE);
            if (is_q)
                EqS[(size_t)(row0 >> 3) * 1024 + a4 * 32 + (qoff + r) * 4 + ac] = e;
            else
                EyT[(size_t)a4 * 12800 + (size_t)(row0 + r) * 4 + ac] = e;
        }
    }
}

// ---------------- K2: raw scores (R14-proven); zero LDS/barriers; 4q -------
__global__ __launch_bounds__(448, 2) void score_kernel(
    const float* __restrict__ EqS,   // [400 qgrp][32][8][4]
    const float4* __restrict__ EyT4, // [32][3200]
    const float* __restrict__ vneg,  // [128] = -2v
    const int*  __restrict__ nwins,  // [B]
    float* __restrict__ s)           // [B][TQ][TY]
{
    const int grp = blockIdx.x;               // b*100 + qg
    const int b   = grp / 100;
    const int qg  = grp % 100;
    const int q0  = qg * 4;
    const int n   = nwins[b];
    const int t   = threadIdx.x;              // 0..447
    if ((t & ~63) >= n) return;               // wave-uniform early exit

    const int ycol = b * TYn + min(t, TYn - 1);
    const float4* eqg = reinterpret_cast<const float4*>(EqS)
                      + (size_t)(b * 50 + (qg >> 1)) * 256 + 4 * (qg & 1);
    const float4* vn4 = reinterpret_cast<const float4*>(vneg);

    float ac0 = 0.f, ac1 = 0.f, ac2 = 0.f, ac3 = 0.f;
    for (int a4 = 0; a4 < 32; ++a4) {
        const float4 ey = EyT4[(size_t)a4 * 3200 + ycol];  // coalesced 1KB
        const float4* eqa = eqg + a4 * 8;                  // uniform -> s_load
        const float4 vv = vn4[a4];                         // uniform -> s_load
        const float4 e0 = eqa[0], e1 = eqa[1], e2 = eqa[2], e3 = eqa[3];
        #define SCORE_Q(ACC, EQ)                                            \
        {                                                                   \
            float a0 = fmaf(EQ.x, ey.x, 1.f);                               \
            float a1 = fmaf(EQ.y, ey.y, 1.f);                               \
            float a2 = fmaf(EQ.z, ey.z, 1.f);                               \
            float a3 = fmaf(EQ.w, ey.w, 1.f);                               \
            float p01 = a0 * a1, p23 = a2 * a3;                             \
            float R = __builtin_amdgcn_rcpf(p01 * p23);                     \
            float u = p23 * R, w = p01 * R;                                 \
            ACC = fmaf(vv.x, a1 * u, ACC);                                  \
            ACC = fmaf(vv.y, a0 * u, ACC);                                  \
            ACC = fmaf(vv.z, a3 * w, ACC);                                  \
            ACC = fmaf(vv.w, a2 * w, ACC);                                  \
        }
        SCORE_Q(ac0, e0) SCORE_Q(ac1, e1) SCORE_Q(ac2, e2) SCORE_Q(ac3, e3)
        #undef SCORE_Q
    }
    if (t < n) {
        float* srow = s + (size_t)(b * TQn + q0) * TYn + t;
        srow[0 * TYn] = ac0; srow[1 * TYn] = ac1;
        srow[2 * TYn] = ac2; srow[3 * TYn] = ac3;
    }
}

// ---------------- K3: softmax + att@y; wave-owns-row apply -----------------
__global__ __launch_bounds__(512, 2) void apply_kernel(
    const float* __restrict__ y,    // [B][TY][DD]
    const float* __restrict__ s,    // [B][TQ][TY]
    const int*  __restrict__ nwins, // [B]
    float* __restrict__ out)        // [B][TQ][DD]
{
    const int bid = blockIdx.x;               // 8 * 50
    const int b   = bid / 50;
    const int q0  = (bid % 50) * 8;
    const int tid = threadIdx.x, wave = tid >> 6, lane = tid & 63;
    const int n = nwins[b];
    const float NEG_INF = -__builtin_inff();

    // 19.2 KB: pT[400][PTS] floats; aliased as [8][2][64] f4 (16 KB) in reduce
    __shared__ __align__(16) float4 s_buf4[1200];
    float* s_pT = reinterpret_cast<float*>(s_buf4);

    // ---- softmax for q = q0 + wave (8 waves, proven form) ----
    const float* srow = s + (size_t)(b * TQn + q0 + wave) * TYn;
    float sc0, sc1, sc2, sc3, sc4, sc5, sc6;
    {
        int t;
        t = 0 * 64 + lane; sc0 = (t < n) ? srow[t] : NEG_INF;
        t = 1 * 64 + lane; sc1 = (t < n) ? srow[t] : NEG_INF;
        t = 2 * 64 + lane; sc2 = (t < n) ? srow[t] : NEG_INF;
        t = 3 * 64 + lane; sc3 = (t < n) ? srow[t] : NEG_INF;
        t = 4 * 64 + lane; sc4 = (t < n) ? srow[t] : NEG_INF;
        t = 5 * 64 + lane; sc5 = (t < n) ? srow[t] : NEG_INF;
        t = 6 * 64 + lane; sc6 = (t < n) ? srow[t] : NEG_INF;
    }
    float m = fmaxf(fmaxf(fmaxf(sc0, sc1), fmaxf(sc2, sc3)),
                    fmaxf(fmaxf(sc4, sc5), sc6));
    #pragma unroll
    for (int off = 32; off >= 1; off >>= 1) m = fmaxf(m, __shfl_xor(m, off, 64));
    sc0 = __builtin_amdgcn_exp2f((sc0 - m) * LOG2E);
    sc1 = __builtin_amdgcn_exp2f((sc1 - m) * LOG2E);
    sc2 = __builtin_amdgcn_exp2f((sc2 - m) * LOG2E);
    sc3 = __builtin_amdgcn_exp2f((sc3 - m) * LOG2E);
    sc4 = __builtin_amdgcn_exp2f((sc4 - m) * LOG2E);
    sc5 = __builtin_amdgcn_exp2f((sc5 - m) * LOG2E);
    sc6 = __builtin_amdgcn_exp2f((sc6 - m) * LOG2E);
    float l = ((sc0 + sc1) + (sc2 + sc3)) + ((sc4 + sc5) + sc6);
    #pragma unroll
    for (int off = 32; off >= 1; off >>= 1) l += __shfl_xor(l, off, 64);
    const float inv = 1.0f / l;
    // publish transposed: pT[t][wave]; zeros beyond n (exp2(-inf)=0)
    s_pT[(0 * 64 + lane) * PTS + wave] = sc0 * inv;
    s_pT[(1 * 64 + lane) * PTS + wave] = sc1 * inv;
    s_pT[(2 * 64 + lane) * PTS + wave] = sc2 * inv;
    s_pT[(3 * 64 + lane) * PTS + wave] = sc3 * inv;
    s_pT[(4 * 64 + lane) * PTS + wave] = sc4 * inv;
    s_pT[(5 * 64 + lane) * PTS + wave] = sc5 * inv;
    {
        const int t = 6 * 64 + lane;          // 384..447
        if (t < TYn) s_pT[t * PTS + wave] = sc6 * inv;
    }
    __syncthreads();                          // pT visible to all waves

    // ---- apply: wave owns rows t = wave + 8*i; lane = d4 (1KB coalesced) ----
    const float4* yb4 = reinterpret_cast<const float4*>(y) + (size_t)(b * TYn) * 64;
    float4 ac0 = {0,0,0,0}, ac1 = {0,0,0,0}, ac2 = {0,0,0,0}, ac3 = {0,0,0,0};
    float4 ac4 = {0,0,0,0}, ac5 = {0,0,0,0}, ac6 = {0,0,0,0}, ac7 = {0,0,0,0};

    // depth-2 pipeline over this wave's 50 rows (p==0 beyond n -> unconditional)
    int tA = wave;
    float4 yA = yb4[(size_t)tA * 64 + lane];
    float4 pa_A = *reinterpret_cast<const float4*>(&s_pT[tA * PTS]);
    float4 pb_A = *reinterpret_cast<const float4*>(&s_pT[tA * PTS + 4]);
    int tB = wave + 8;
    float4 yB = yb4[(size_t)tB * 64 + lane];
    float4 pa_B = *reinterpret_cast<const float4*>(&s_pT[tB * PTS]);
    float4 pb_B = *reinterpret_cast<const float4*>(&s_pT[tB * PTS + 4]);

    #define ACCUM(PA, PB, YV)                                               \
        ac0.x = fmaf(PA.x, YV.x, ac0.x); ac0.y = fmaf(PA.x, YV.y, ac0.y);   \
        ac0.z = fmaf(PA.x, YV.z, ac0.z); ac0.w = fmaf(PA.x, YV.w, ac0.w);   \
        ac1.x = fmaf(PA.y, YV.x, ac1.x); ac1.y = fmaf(PA.y, YV.y, ac1.y);   \
        ac1.z = fmaf(PA.y, YV.z, ac1.z); ac1.w = fmaf(PA.y, YV.w, ac1.w);   \
        ac2.x = fmaf(PA.z, YV.x, ac2.x); ac2.y = fmaf(PA.z, YV.y, ac2.y);   \
        ac2.z = fmaf(PA.z, YV.z, ac2.z); ac2.w = fmaf(PA.z, YV.w, ac2.w);   \
        ac3.x = fmaf(PA.w, YV.x, ac3.x); ac3.y = fmaf(PA.w, YV.y, ac3.y);   \
        ac3.z = fmaf(PA.w, YV.z, ac3.z); ac3.w = fmaf(PA.w, YV.w, ac3.w);   \
        ac4.x = fmaf(PB.x, YV.x, ac4.x); ac4.y = fmaf(PB.x, YV.y, ac4.y);   \
        ac4.z = fmaf(PB.x, YV.z, ac4.z); ac4.w = fmaf(PB.x, YV.w, ac4.w);   \
        ac5.x = fmaf(PB.y, YV.x, ac5.x); ac5.y = fmaf(PB.y, YV.y, ac5.y);   \
        ac5.z = fmaf(PB.y, YV.z, ac5.z); ac5.w = fmaf(PB.y, YV.w, ac5.w);   \
        ac6.x = fmaf(PB.z, YV.x, ac6.x); ac6.y = fmaf(PB.z, YV.y, ac6.y);   \
        ac6.z = fmaf(PB.z, YV.z, ac6.z); ac6.w = fmaf(PB.z, YV.w, ac6.w);   \
        ac7.x = fmaf(PB.w, YV.x, ac7.x); ac7.y = fmaf(PB.w, YV.y, ac7.y);   \
        ac7.z = fmaf(PB.w, YV.z, ac7.z); ac7.w = fmaf(PB.w, YV.w, ac7.w);

    for (int i = 0; i < 25; ++i) {            // 2 rows per iter
        {   // row tA
            const float4 pa = pa_A, pb = pb_A, yv = yA;
            const int tn = tA + 16;
            if (i < 24) {
                yA = yb4[(size_t)tn * 64 + lane];
                pa_A = *reinterpret_cast<const float4*>(&s_pT[tn * PTS]);
                pb_A = *reinterpret_cast<const float4*>(&s_pT[tn * PTS + 4]);
                tA = tn;
            }
            ACCUM(pa, pb, yv)
        }
        {   // row tB
            const float4 pa = pa_B, pb = pb_B, yv = yB;
            const int tn = tB + 16;
            if (i < 24) {
                yB = yb4[(size_t)tn * 64 + lane];
                pa_B = *reinterpret_cast<const float4*>(&s_pT[tn * PTS]);
                pb_B = *reinterpret_cast<const float4*>(&s_pT[tn * PTS + 4]);
                tB = tn;
            }
            ACCUM(pa, pb, yv)
        }
    }
    #undef ACCUM

    // ---- cross-wave reduce: 4 phases x (2 q), buffer aliases pT ----
    float4* rbuf = s_buf4;                    // [8 w][2 qi][64 d4]
    float4* o4 = reinterpret_cast<float4*>(out) + (size_t)(b * TQn + q0) * 64;
    auto rphase = [&](float4 AQ, float4 BQ, int PH) {
        __syncthreads();  // prior phase reads (or pT reads) done
        rbuf[wave * 128 + lane]      = AQ;
        rbuf[wave * 128 + 64 + lane] = BQ;
        __syncthreads();
        if (tid < 128) {
            const int qi = tid >> 6, dr = tid & 63;
            float4 s0 = rbuf[0 * 128 + qi * 64 + dr];
            #pragma unroll
            for (int w2 = 1; w2 < 8; ++w2) {
                float4 v = rbuf[w2 * 128 + qi * 64 + dr];
                s0.x += v.x; s0.y += v.y; s0.z += v.z; s0.w += v.w;
            }
            o4[(size_t)(PH * 2 + qi) * 64 + dr] = s0;
        }
    };
    rphase(ac0, ac1, 0);
    rphase(ac2, ac3, 1);
    rphase(ac4, ac5, 2);
    rphase(ac6, ac7, 3);
}

extern "C" void kernel_launch(void* const* d_in, const int* in_sizes, int n_in,
                              void* d_out, int out_size, void* d_ws, size_t ws_size,
                              hipStream_t stream) {
    const float* query = (const float*)d_in[0];
    const float* y     = (const float*)d_in[1];
    const float* Wq_w  = (const float*)d_in[2];
    const float* Wq_b  = (const float*)d_in[3];
    const float* Wy_w  = (const float*)d_in[4];
    const float* Wy_b  = (const float*)d_in[5];
    const float* v_w   = (const float*)d_in[6];
    // d_in[7] = v_b: softmax-invariant, dropped.
    const int* nw      = (const int*)d_in[8];
    float* out = (float*)d_out;

    float4* WTq  = (float4*)d_ws;                    // 131 KB
    float4* WTy  = WTq + 64 * 128;                   // 131 KB
    float*  vneg = (float*)(WTy + 64 * 128);         // 512 B (pad 1 KB)
    float*  EqS  = vneg + 256;                       // [400][32][8][4] = 1.64 MB
    float*  EyT  = EqS + (size_t)400 * 1024;         // [32][3200][4]  = 1.64 MB
    float*  s    = EyT + (size_t)32 * 3200 * 4;      // [8][400][400]  = 5.12 MB

    transpose_kernel<<<128, 128, 0, stream>>>(Wq_w, Wy_w, v_w, WTq, WTy, vneg);
    proj_kernel<<<1600, 256, 0, stream>>>(query, y, WTq, Wq_b, WTy, Wy_b, EqS, EyT);
    score_kernel<<<8 * 100, 448, 0, stream>>>(
        EqS, (const float4*)EyT, vneg, nw, s);
    apply_kernel<<<8 * 50, 512, 0, stream>>>(y, s, nw, out);
}